// Round 2
// baseline (581.054 us; speedup 1.0000x reference)
//
#include <hip/hip_runtime.h>
#include <hip/hip_bf16.h>

// Problem: b=2, s=4096, d_model=512, heads=8, d_head=64.
// Inputs/outputs are FLOAT32 (per reference); internal compute bf16 MFMA.

typedef __attribute__((ext_vector_type(4))) float  f32x4;
typedef __attribute__((ext_vector_type(8))) __bf16 bf16x8;
typedef __attribute__((ext_vector_type(8))) unsigned short u16x8;

#define MFMA16(a, b, c) __builtin_amdgcn_mfma_f32_16x16x32_bf16((a), (b), (c), 0, 0, 0)

static __device__ __forceinline__ bf16x8 ld8(const __hip_bfloat16* p) {
    return *reinterpret_cast<const bf16x8*>(p);
}
static __device__ __forceinline__ __hip_bfloat16 tobf(float f) {
    return __float2bfloat16(f);
}

// ---------------------------------------------------------------------------
// Cast kernel: float32 -> bf16, 8 elements per thread.
// ---------------------------------------------------------------------------
__global__ __launch_bounds__(256) void cast_f32_bf16(
    const float* __restrict__ in, __hip_bfloat16* __restrict__ out, int n8)
{
    const int i = blockIdx.x * 256 + threadIdx.x;
    if (i >= n8) return;
    const float4 a = *reinterpret_cast<const float4*>(in + (size_t)i * 8);
    const float4 b = *reinterpret_cast<const float4*>(in + (size_t)i * 8 + 4);
    u16x8 o;
    o[0] = __bfloat16_as_ushort(tobf(a.x));
    o[1] = __bfloat16_as_ushort(tobf(a.y));
    o[2] = __bfloat16_as_ushort(tobf(a.z));
    o[3] = __bfloat16_as_ushort(tobf(a.w));
    o[4] = __bfloat16_as_ushort(tobf(b.x));
    o[5] = __bfloat16_as_ushort(tobf(b.y));
    o[6] = __bfloat16_as_ushort(tobf(b.z));
    o[7] = __bfloat16_as_ushort(tobf(b.w));
    *reinterpret_cast<u16x8*>(out + (size_t)i * 8) = o;
}

// ---------------------------------------------------------------------------
// Kernel 1: QKV projection. grid = (128 m-tiles, 8 heads, 3 {K,Q,V}), block 256.
// A = x [8192 x 512] row-major bf16, B = W[h] [64 x 512] row-major (B^T form).
// Q pre-scaled by 1/sqrt(64)=0.125. V stored transposed [bh][64][4096].
// ---------------------------------------------------------------------------
__global__ __launch_bounds__(256) void qkv_proj(
    const __hip_bfloat16* __restrict__ x,
    const __hip_bfloat16* __restrict__ Wk,
    const __hip_bfloat16* __restrict__ Wq,
    const __hip_bfloat16* __restrict__ Wv,
    __hip_bfloat16* __restrict__ Qo,   // [16][4096][64]
    __hip_bfloat16* __restrict__ Ko,   // [16][4096][64]
    __hip_bfloat16* __restrict__ Vt)   // [16][64][4096]
{
    const int w    = threadIdx.x >> 6;
    const int lane = threadIdx.x & 63;
    const int l16  = lane & 15;
    const int lg   = lane >> 4;
    const int mt   = blockIdx.x;
    const int h    = blockIdx.y;
    const int z    = blockIdx.z;

    const __hip_bfloat16* W =
        (z == 0 ? Wk : (z == 1 ? Wq : Wv)) + (size_t)h * 64 * 512;

    const int arow = mt * 64 + w * 16 + l16;
    const __hip_bfloat16* Ap = x + (size_t)arow * 512 + lg * 8;

    f32x4 acc[4] = {};
    for (int k0 = 0; k0 < 512; k0 += 32) {
        bf16x8 a = ld8(Ap + k0);
#pragma unroll
        for (int nf = 0; nf < 4; ++nf) {
            bf16x8 b = ld8(W + (size_t)(nf * 16 + l16) * 512 + k0 + lg * 8);
            acc[nf] = MFMA16(a, b, acc[nf]);
        }
    }

    const int rowbase = mt * 64 + w * 16 + lg * 4;
    const float scale = (z == 1) ? 0.125f : 1.0f;
#pragma unroll
    for (int nf = 0; nf < 4; ++nf) {
#pragma unroll
        for (int r = 0; r < 4; ++r) {
            const int row  = rowbase + r;
            const int bq   = row >> 12;
            const int srow = row & 4095;
            const int bh   = bq * 8 + h;
            const int col  = nf * 16 + l16;
            const float v  = acc[nf][r] * scale;
            if (z == 2) {
                Vt[((size_t)bh * 64 + col) * 4096 + srow] = tobf(v);
            } else if (z == 0) {
                Ko[((size_t)bh * 4096 + srow) * 64 + col] = tobf(v);
            } else {
                Qo[((size_t)bh * 4096 + srow) * 64 + col] = tobf(v);
            }
        }
    }
}

// ---------------------------------------------------------------------------
// Kernel 2: causal flash attention. grid = (64 q-tiles, 16 bh), block 256.
// Each wave owns 16 q-rows; KV tiles of 64; online softmax in registers.
// ---------------------------------------------------------------------------
__global__ __launch_bounds__(256) void attn_fwd(
    const __hip_bfloat16* __restrict__ Q,
    const __hip_bfloat16* __restrict__ K,
    const __hip_bfloat16* __restrict__ Vt,
    __hip_bfloat16* __restrict__ Z)    // [b][s][h*64]
{
    __shared__ __hip_bfloat16 lds_p[4][16][72];

    const int w    = threadIdx.x >> 6;
    const int lane = threadIdx.x & 63;
    const int l16  = lane & 15;
    const int lg   = lane >> 4;
    const int qt   = (int)gridDim.x - 1 - (int)blockIdx.x;  // longest first
    const int bh   = blockIdx.y;
    const int qbase = qt * 64 + w * 16;

    const __hip_bfloat16* Qb = Q  + (size_t)bh * 4096 * 64;
    const __hip_bfloat16* Kb = K  + (size_t)bh * 4096 * 64;
    const __hip_bfloat16* Vb = Vt + (size_t)bh * 64 * 4096;

    bf16x8 qf[2];
#pragma unroll
    for (int ks = 0; ks < 2; ++ks)
        qf[ks] = ld8(Qb + (size_t)(qbase + l16) * 64 + ks * 32 + lg * 8);

    f32x4 zacc[4] = {};
    float m_r[4], l_r[4];
#pragma unroll
    for (int r = 0; r < 4; ++r) { m_r[r] = -3.0e38f; l_r[r] = 0.0f; }

    const int nt = qt + 1;
    for (int t = 0; t < nt; ++t) {
        const int p0 = t * 64;

        // ---- S = Q K^T (16q x 64p per wave) ----
        f32x4 sacc[4] = {};
#pragma unroll
        for (int pf = 0; pf < 4; ++pf) {
#pragma unroll
            for (int ks = 0; ks < 2; ++ks) {
                bf16x8 kf = ld8(Kb + (size_t)(p0 + pf * 16 + l16) * 64 + ks * 32 + lg * 8);
                sacc[pf] = MFMA16(qf[ks], kf, sacc[pf]);
            }
        }

        // ---- causal mask + online softmax ----
        float pvals[4][4];   // [r][pf]
#pragma unroll
        for (int r = 0; r < 4; ++r) {
            const int qrow = qbase + lg * 4 + r;
            float rm = -3.0e38f;
#pragma unroll
            for (int pf = 0; pf < 4; ++pf) {
                float s = sacc[pf][r];
                const int p = p0 + pf * 16 + l16;
                s = (p <= qrow) ? s : -1.0e30f;
                sacc[pf][r] = s;
                rm = fmaxf(rm, s);
            }
            rm = fmaxf(rm, __shfl_xor(rm, 1));
            rm = fmaxf(rm, __shfl_xor(rm, 2));
            rm = fmaxf(rm, __shfl_xor(rm, 4));
            rm = fmaxf(rm, __shfl_xor(rm, 8));
            const float mnew  = fmaxf(m_r[r], rm);
            const float alpha = __expf(m_r[r] - mnew);
            m_r[r] = mnew;
            float rs = 0.0f;
#pragma unroll
            for (int pf = 0; pf < 4; ++pf) {
                const float e = __expf(sacc[pf][r] - mnew);
                pvals[r][pf] = e;
                rs += e;
            }
            rs += __shfl_xor(rs, 1);
            rs += __shfl_xor(rs, 2);
            rs += __shfl_xor(rs, 4);
            rs += __shfl_xor(rs, 8);
            l_r[r] = l_r[r] * alpha + rs;
#pragma unroll
            for (int df = 0; df < 4; ++df) zacc[df][r] *= alpha;
        }

        // ---- transpose P through LDS (wave-private region) ----
        __syncthreads();
#pragma unroll
        for (int r = 0; r < 4; ++r)
#pragma unroll
            for (int pf = 0; pf < 4; ++pf)
                lds_p[w][lg * 4 + r][pf * 16 + l16] = tobf(pvals[r][pf]);
        __syncthreads();

        bf16x8 pa[2];
#pragma unroll
        for (int ks = 0; ks < 2; ++ks)
            pa[ks] = *reinterpret_cast<const bf16x8*>(&lds_p[w][l16][ks * 32 + lg * 8]);

        // ---- Z += P V  (V^T rows contiguous over p) ----
#pragma unroll
        for (int df = 0; df < 4; ++df) {
#pragma unroll
            for (int ks = 0; ks < 2; ++ks) {
                bf16x8 vf = ld8(Vb + (size_t)(df * 16 + l16) * 4096 + p0 + ks * 32 + lg * 8);
                zacc[df] = MFMA16(pa[ks], vf, zacc[df]);
            }
        }
    }

    // ---- epilogue ----
    const int b = bh >> 3, h = bh & 7;
#pragma unroll
    for (int df = 0; df < 4; ++df)
#pragma unroll
        for (int r = 0; r < 4; ++r) {
            const int qrow = qbase + lg * 4 + r;
            const float v  = zacc[df][r] / l_r[r];
            Z[((size_t)b * 4096 + qrow) * 512 + h * 64 + df * 16 + l16] = tobf(v);
        }
}

// ---------------------------------------------------------------------------
// Kernel 3: output projection -> FLOAT32 out.
// ---------------------------------------------------------------------------
__global__ __launch_bounds__(256) void out_proj(
    const __hip_bfloat16* __restrict__ Zf,   // [8192][512]
    const __hip_bfloat16* __restrict__ Wo,   // [512][512] bf16
    float* __restrict__ out)                 // [8192][512] f32
{
    const int w    = threadIdx.x >> 6;
    const int lane = threadIdx.x & 63;
    const int l16  = lane & 15;
    const int lg   = lane >> 4;
    const int r0   = blockIdx.x * 64 + w * 16;
    const int n0   = blockIdx.y * 64;

    f32x4 acc[4] = {};
    const __hip_bfloat16* Ap = Zf + (size_t)(r0 + l16) * 512 + lg * 8;
    for (int k0 = 0; k0 < 512; k0 += 32) {
        bf16x8 a = ld8(Ap + k0);
#pragma unroll
        for (int nf = 0; nf < 4; ++nf) {
            bf16x8 b = ld8(Wo + (size_t)(n0 + nf * 16 + l16) * 512 + k0 + lg * 8);
            acc[nf] = MFMA16(a, b, acc[nf]);
        }
    }
#pragma unroll
    for (int nf = 0; nf < 4; ++nf)
#pragma unroll
        for (int r = 0; r < 4; ++r)
            out[(size_t)(r0 + lg * 4 + r) * 512 + n0 + nf * 16 + l16] = acc[nf][r];
}

// ---------------------------------------------------------------------------
extern "C" void kernel_launch(void* const* d_in, const int* in_sizes, int n_in,
                              void* d_out, int out_size, void* d_ws, size_t ws_size,
                              hipStream_t stream)
{
    // setup_inputs() order: x, W_K, W_Q, W_V, W_O — all FLOAT32 on device.
    const float* x_f  = (const float*)d_in[0];
    const float* Wk_f = (const float*)d_in[1];
    const float* Wq_f = (const float*)d_in[2];
    const float* Wv_f = (const float*)d_in[3];
    const float* Wo_f = (const float*)d_in[4];
    float* out = (float*)d_out;

    char* ws = (char*)d_ws;
    const size_t szQKV = (size_t)16 * 4096 * 64 * sizeof(__hip_bfloat16);   // 8 MB
    const size_t szX   = (size_t)8192 * 512 * sizeof(__hip_bfloat16);      // 8 MB
    const size_t szW   = (size_t)8 * 64 * 512 * sizeof(__hip_bfloat16);    // 0.5 MB
    size_t off = 0;
    __hip_bfloat16* Qb  = (__hip_bfloat16*)(ws + off); off += szQKV;
    __hip_bfloat16* Kb  = (__hip_bfloat16*)(ws + off); off += szQKV;
    __hip_bfloat16* Vt  = (__hip_bfloat16*)(ws + off); off += szQKV;
    __hip_bfloat16* Zb  = (__hip_bfloat16*)(ws + off); off += szX;  // [8192][512]
    __hip_bfloat16* xb  = (__hip_bfloat16*)(ws + off); off += szX;  // [8192][512]
    __hip_bfloat16* Wkb = (__hip_bfloat16*)(ws + off); off += szW;
    __hip_bfloat16* Wqb = (__hip_bfloat16*)(ws + off); off += szW;
    __hip_bfloat16* Wvb = (__hip_bfloat16*)(ws + off); off += szW;
    __hip_bfloat16* Wob = (__hip_bfloat16*)(ws + off); off += szW;

    // f32 -> bf16 casts
    {
        const int nx = 8192 * 512 / 8;       // 524288 threads
        cast_f32_bf16<<<nx / 256, 256, 0, stream>>>(x_f, xb, nx);
        const int nw = 8 * 64 * 512 / 8;     // 32768 threads
        cast_f32_bf16<<<nw / 256, 256, 0, stream>>>(Wk_f, Wkb, nw);
        cast_f32_bf16<<<nw / 256, 256, 0, stream>>>(Wq_f, Wqb, nw);
        cast_f32_bf16<<<nw / 256, 256, 0, stream>>>(Wv_f, Wvb, nw);
        cast_f32_bf16<<<nw / 256, 256, 0, stream>>>(Wo_f, Wob, nw);
    }

    qkv_proj<<<dim3(128, 8, 3), 256, 0, stream>>>(xb, Wkb, Wqb, Wvb, Qb, Kb, Vt);
    attn_fwd<<<dim3(64, 16),    256, 0, stream>>>(Qb, Kb, Vt, Zb);
    out_proj<<<dim3(128, 8),    256, 0, stream>>>(Zb, Wob, out);
}

// Round 3
// 556.218 us; speedup vs baseline: 1.0447x; 1.0447x over previous
//
#include <hip/hip_runtime.h>
#include <hip/hip_bf16.h>

// Problem: b=2, s=4096, d_model=512, heads=8, d_head=64.
// Inputs/outputs FLOAT32; internal compute bf16 MFMA.

typedef __attribute__((ext_vector_type(4))) float  f32x4;
typedef __attribute__((ext_vector_type(8))) __bf16 bf16x8;
typedef __attribute__((ext_vector_type(8))) unsigned short u16x8;

#define MFMA16(a, b, c) __builtin_amdgcn_mfma_f32_16x16x32_bf16((a), (b), (c), 0, 0, 0)

static __device__ __forceinline__ bf16x8 ld8(const __hip_bfloat16* p) {
    return *reinterpret_cast<const bf16x8*>(p);
}
static __device__ __forceinline__ __hip_bfloat16 tobf(float f) {
    return __float2bfloat16(f);
}

// ---------------------------------------------------------------------------
// Cast kernel: float32 -> bf16, 8 elements per thread.
// ---------------------------------------------------------------------------
__global__ __launch_bounds__(256) void cast_f32_bf16(
    const float* __restrict__ in, __hip_bfloat16* __restrict__ out, int n8)
{
    const int i = blockIdx.x * 256 + threadIdx.x;
    if (i >= n8) return;
    const float4 a = *reinterpret_cast<const float4*>(in + (size_t)i * 8);
    const float4 b = *reinterpret_cast<const float4*>(in + (size_t)i * 8 + 4);
    u16x8 o;
    o[0] = __bfloat16_as_ushort(tobf(a.x));
    o[1] = __bfloat16_as_ushort(tobf(a.y));
    o[2] = __bfloat16_as_ushort(tobf(a.z));
    o[3] = __bfloat16_as_ushort(tobf(a.w));
    o[4] = __bfloat16_as_ushort(tobf(b.x));
    o[5] = __bfloat16_as_ushort(tobf(b.y));
    o[6] = __bfloat16_as_ushort(tobf(b.z));
    o[7] = __bfloat16_as_ushort(tobf(b.w));
    *reinterpret_cast<u16x8*>(out + (size_t)i * 8) = o;
}

// ---------------------------------------------------------------------------
// Kernel 1: QKV projection. grid = (128 m-tiles, 8 heads, 3 {K,Q,V}), block 256.
// ---------------------------------------------------------------------------
__global__ __launch_bounds__(256) void qkv_proj(
    const __hip_bfloat16* __restrict__ x,
    const __hip_bfloat16* __restrict__ Wk,
    const __hip_bfloat16* __restrict__ Wq,
    const __hip_bfloat16* __restrict__ Wv,
    __hip_bfloat16* __restrict__ Qo,   // [16][4096][64]
    __hip_bfloat16* __restrict__ Ko,   // [16][4096][64]
    __hip_bfloat16* __restrict__ Vt)   // [16][64][4096]
{
    const int w    = threadIdx.x >> 6;
    const int lane = threadIdx.x & 63;
    const int l16  = lane & 15;
    const int lg   = lane >> 4;
    const int mt   = blockIdx.x;
    const int h    = blockIdx.y;
    const int z    = blockIdx.z;

    const __hip_bfloat16* W =
        (z == 0 ? Wk : (z == 1 ? Wq : Wv)) + (size_t)h * 64 * 512;

    const int arow = mt * 64 + w * 16 + l16;
    const __hip_bfloat16* Ap = x + (size_t)arow * 512 + lg * 8;

    f32x4 acc[4] = {};
    for (int k0 = 0; k0 < 512; k0 += 32) {
        bf16x8 a = ld8(Ap + k0);
#pragma unroll
        for (int nf = 0; nf < 4; ++nf) {
            bf16x8 b = ld8(W + (size_t)(nf * 16 + l16) * 512 + k0 + lg * 8);
            acc[nf] = MFMA16(a, b, acc[nf]);
        }
    }

    const int rowbase = mt * 64 + w * 16 + lg * 4;
    const float scale = (z == 1) ? 0.125f : 1.0f;
#pragma unroll
    for (int nf = 0; nf < 4; ++nf) {
#pragma unroll
        for (int r = 0; r < 4; ++r) {
            const int row  = rowbase + r;
            const int bq   = row >> 12;
            const int srow = row & 4095;
            const int bh   = bq * 8 + h;
            const int col  = nf * 16 + l16;
            const float v  = acc[nf][r] * scale;
            if (z == 2) {
                Vt[((size_t)bh * 64 + col) * 4096 + srow] = tobf(v);
            } else if (z == 0) {
                Ko[((size_t)bh * 4096 + srow) * 64 + col] = tobf(v);
            } else {
                Qo[((size_t)bh * 4096 + srow) * 64 + col] = tobf(v);
            }
        }
    }
}

// ---------------------------------------------------------------------------
// Kernel 2: causal flash attention, swapped-QK^T form.
// grid = (64 q-tiles, 16 bh), block 256 (4 waves x 16 q-rows).
//
// S^T = mfma(K, Q): lane holds S[p][q] for q = lane&15 (one q-row per lane),
// p = pf*16 + (lane>>4)*4 + r  -> softmax is in-lane + 2 shfl_xor reduces.
// P transposed through wave-private LDS (no barriers needed), PV unchanged.
// ---------------------------------------------------------------------------
__global__ __launch_bounds__(256) void attn_fwd(
    const __hip_bfloat16* __restrict__ Q,
    const __hip_bfloat16* __restrict__ K,
    const __hip_bfloat16* __restrict__ Vt,
    __hip_bfloat16* __restrict__ Z)    // [b][s][h*64]
{
    __shared__ __hip_bfloat16 lds_p[4][16][72];   // wave-private [w][q][p]

    const int w    = threadIdx.x >> 6;
    const int lane = threadIdx.x & 63;
    const int l16  = lane & 15;
    const int lg   = lane >> 4;
    const int qt   = (int)gridDim.x - 1 - (int)blockIdx.x;  // longest first
    const int bh   = blockIdx.y;
    const int qbase = qt * 64 + w * 16;

    const __hip_bfloat16* Qb = Q  + (size_t)bh * 4096 * 64;
    const __hip_bfloat16* Kb = K  + (size_t)bh * 4096 * 64;
    const __hip_bfloat16* Vb = Vt + (size_t)bh * 64 * 4096;

    bf16x8 qf[2];
#pragma unroll
    for (int ks = 0; ks < 2; ++ks)
        qf[ks] = ld8(Qb + (size_t)(qbase + l16) * 64 + ks * 32 + lg * 8);

    f32x4 zacc[4] = {};
    float m_s = -3.0e38f;   // running max of q-row (q = qbase + l16)
    float l_s = 0.0f;       // running denom

    const int nt = qt + 1;
    const int qrow_s = qbase + l16;          // this lane's softmax q-row

    for (int t = 0; t < nt; ++t) {
        const int p0 = t * 64;

        // ---- S^T = K Q^T (64p x 16q per wave), swapped operands ----
        f32x4 sacc[4] = {};
#pragma unroll
        for (int pf = 0; pf < 4; ++pf) {
#pragma unroll
            for (int ks = 0; ks < 2; ++ks) {
                bf16x8 kf = ld8(Kb + (size_t)(p0 + pf * 16 + l16) * 64 + ks * 32 + lg * 8);
                sacc[pf] = MFMA16(kf, qf[ks], sacc[pf]);   // A=K, B=Q -> S^T
            }
        }

        // ---- causal mask + in-lane softmax (lane owns q-row qrow_s) ----
        float rm = -3.0e38f;
#pragma unroll
        for (int pf = 0; pf < 4; ++pf)
#pragma unroll
            for (int r = 0; r < 4; ++r) {
                const int p = p0 + pf * 16 + lg * 4 + r;
                float s = sacc[pf][r];
                s = (p <= qrow_s) ? s : -1.0e30f;
                sacc[pf][r] = s;
                rm = fmaxf(rm, s);
            }
        rm = fmaxf(rm, __shfl_xor(rm, 16));
        rm = fmaxf(rm, __shfl_xor(rm, 32));

        const float mnew  = fmaxf(m_s, rm);
        const float alpha = __expf(m_s - mnew);
        m_s = mnew;

        float rs = 0.0f;
        float pv[4][4];
#pragma unroll
        for (int pf = 0; pf < 4; ++pf)
#pragma unroll
            for (int r = 0; r < 4; ++r) {
                const float e = __expf(sacc[pf][r] - mnew);
                pv[pf][r] = e;
                rs += e;
            }
        rs += __shfl_xor(rs, 16);
        rs += __shfl_xor(rs, 32);
        l_s = l_s * alpha + rs;

        // ---- write P^T slice to wave-private LDS: row q=l16, col p ----
#pragma unroll
        for (int pf = 0; pf < 4; ++pf) {
            ushort4 pk;
            pk.x = __bfloat16_as_ushort(tobf(pv[pf][0]));
            pk.y = __bfloat16_as_ushort(tobf(pv[pf][1]));
            pk.z = __bfloat16_as_ushort(tobf(pv[pf][2]));
            pk.w = __bfloat16_as_ushort(tobf(pv[pf][3]));
            *reinterpret_cast<ushort4*>(&lds_p[w][l16][pf * 16 + lg * 4]) = pk;
        }

        // ---- rescale Z accumulators (q = lg*4 + r there) ----
        float alpha_q[4];
#pragma unroll
        for (int r = 0; r < 4; ++r) alpha_q[r] = __shfl(alpha, lg * 4 + r);
#pragma unroll
        for (int df = 0; df < 4; ++df)
#pragma unroll
            for (int r = 0; r < 4; ++r) zacc[df][r] *= alpha_q[r];

        // ---- read P as A-operand, Z += P V ----
        bf16x8 pa[2];
#pragma unroll
        for (int ks = 0; ks < 2; ++ks)
            pa[ks] = *reinterpret_cast<const bf16x8*>(&lds_p[w][l16][ks * 32 + lg * 8]);

#pragma unroll
        for (int df = 0; df < 4; ++df) {
#pragma unroll
            for (int ks = 0; ks < 2; ++ks) {
                bf16x8 vf = ld8(Vb + (size_t)(df * 16 + l16) * 4096 + p0 + ks * 32 + lg * 8);
                zacc[df] = MFMA16(pa[ks], vf, zacc[df]);
            }
        }
    }

    // ---- epilogue: divide by l (broadcast to q = lg*4 + r), write Z ----
    float l_q[4];
#pragma unroll
    for (int r = 0; r < 4; ++r) l_q[r] = __shfl(l_s, lg * 4 + r);

    const int b = bh >> 3, h = bh & 7;
#pragma unroll
    for (int df = 0; df < 4; ++df)
#pragma unroll
        for (int r = 0; r < 4; ++r) {
            const int qrow = qbase + lg * 4 + r;
            const float v  = zacc[df][r] / l_q[r];
            Z[((size_t)b * 4096 + qrow) * 512 + h * 64 + df * 16 + l16] = tobf(v);
        }
}

// ---------------------------------------------------------------------------
// Kernel 3: output projection -> FLOAT32 out.
// ---------------------------------------------------------------------------
__global__ __launch_bounds__(256) void out_proj(
    const __hip_bfloat16* __restrict__ Zf,   // [8192][512]
    const __hip_bfloat16* __restrict__ Wo,   // [512][512] bf16
    float* __restrict__ out)                 // [8192][512] f32
{
    const int w    = threadIdx.x >> 6;
    const int lane = threadIdx.x & 63;
    const int l16  = lane & 15;
    const int lg   = lane >> 4;
    const int r0   = blockIdx.x * 64 + w * 16;
    const int n0   = blockIdx.y * 64;

    f32x4 acc[4] = {};
    const __hip_bfloat16* Ap = Zf + (size_t)(r0 + l16) * 512 + lg * 8;
    for (int k0 = 0; k0 < 512; k0 += 32) {
        bf16x8 a = ld8(Ap + k0);
#pragma unroll
        for (int nf = 0; nf < 4; ++nf) {
            bf16x8 b = ld8(Wo + (size_t)(n0 + nf * 16 + l16) * 512 + k0 + lg * 8);
            acc[nf] = MFMA16(a, b, acc[nf]);
        }
    }
#pragma unroll
    for (int nf = 0; nf < 4; ++nf)
#pragma unroll
        for (int r = 0; r < 4; ++r)
            out[(size_t)(r0 + lg * 4 + r) * 512 + n0 + nf * 16 + l16] = acc[nf][r];
}

// ---------------------------------------------------------------------------
extern "C" void kernel_launch(void* const* d_in, const int* in_sizes, int n_in,
                              void* d_out, int out_size, void* d_ws, size_t ws_size,
                              hipStream_t stream)
{
    const float* x_f  = (const float*)d_in[0];
    const float* Wk_f = (const float*)d_in[1];
    const float* Wq_f = (const float*)d_in[2];
    const float* Wv_f = (const float*)d_in[3];
    const float* Wo_f = (const float*)d_in[4];
    float* out = (float*)d_out;

    char* ws = (char*)d_ws;
    const size_t szQKV = (size_t)16 * 4096 * 64 * sizeof(__hip_bfloat16);   // 8 MB
    const size_t szX   = (size_t)8192 * 512 * sizeof(__hip_bfloat16);      // 8 MB
    const size_t szW   = (size_t)8 * 64 * 512 * sizeof(__hip_bfloat16);    // 0.5 MB
    size_t off = 0;
    __hip_bfloat16* Qb  = (__hip_bfloat16*)(ws + off); off += szQKV;
    __hip_bfloat16* Kb  = (__hip_bfloat16*)(ws + off); off += szQKV;
    __hip_bfloat16* Vt  = (__hip_bfloat16*)(ws + off); off += szQKV;
    __hip_bfloat16* Zb  = (__hip_bfloat16*)(ws + off); off += szX;
    __hip_bfloat16* xb  = (__hip_bfloat16*)(ws + off); off += szX;
    __hip_bfloat16* Wkb = (__hip_bfloat16*)(ws + off); off += szW;
    __hip_bfloat16* Wqb = (__hip_bfloat16*)(ws + off); off += szW;
    __hip_bfloat16* Wvb = (__hip_bfloat16*)(ws + off); off += szW;
    __hip_bfloat16* Wob = (__hip_bfloat16*)(ws + off); off += szW;

    {
        const int nx = 8192 * 512 / 8;
        cast_f32_bf16<<<nx / 256, 256, 0, stream>>>(x_f, xb, nx);
        const int nw = 8 * 64 * 512 / 8;
        cast_f32_bf16<<<nw / 256, 256, 0, stream>>>(Wk_f, Wkb, nw);
        cast_f32_bf16<<<nw / 256, 256, 0, stream>>>(Wq_f, Wqb, nw);
        cast_f32_bf16<<<nw / 256, 256, 0, stream>>>(Wv_f, Wvb, nw);
        cast_f32_bf16<<<nw / 256, 256, 0, stream>>>(Wo_f, Wob, nw);
    }

    qkv_proj<<<dim3(128, 8, 3), 256, 0, stream>>>(xb, Wkb, Wqb, Wvb, Qb, Kb, Vt);
    attn_fwd<<<dim3(64, 16),    256, 0, stream>>>(Qb, Kb, Vt, Zb);
    out_proj<<<dim3(128, 8),    256, 0, stream>>>(Zb, Wob, out);
}